// Round 2
// baseline (965.285 us; speedup 1.0000x reference)
//
#include <hip/hip_runtime.h>

#define B_ 2
#define T_ 2048
#define H_ 16
#define D_ 128
#define DM_ 2048
#define CL_ 2048
#define KV_ 4096

typedef __attribute__((ext_vector_type(8))) short short8;
typedef __attribute__((ext_vector_type(4))) float f32x4;
typedef unsigned short u16;

__device__ __forceinline__ u16 f2bf(float f) {
    unsigned u = __float_as_uint(f);
    u += 0x7FFFu + ((u >> 16) & 1u);   // RNE to bf16
    return (u16)(u >> 16);
}

__device__ __forceinline__ void gload16(const void* g, void* l) {
    __builtin_amdgcn_global_load_lds((__attribute__((address_space(1))) const void*)g,
                                     (__attribute__((address_space(3))) void*)l, 16, 0, 0);
}

// ---------------- conversions ----------------

__global__ void cvt4(const float* __restrict__ src, u16* __restrict__ dst, int n4) {
    int i = blockIdx.x * 256 + threadIdx.x;
    if (i >= n4) return;
    const float4 v = *(const float4*)(src + (long)i * 4);
    ushort4 o;
    o.x = f2bf(v.x); o.y = f2bf(v.y); o.z = f2bf(v.z); o.w = f2bf(v.w);
    *(ushort4*)(dst + (long)i * 4) = o;
}

// cache_k f32 [bh][s(2048)][d] -> Kb bf16 [bh][s within 4096][d]
__global__ void cvt_cachek(const float* __restrict__ ck, u16* __restrict__ Kb) {
    long e = ((long)blockIdx.x * 256 + threadIdx.x) * 4;
    int bh = (int)(e >> 18);          // 2048*128 = 262144
    int rem = (int)(e & 262143);
    const float4 v = *(const float4*)(ck + e);
    ushort4 o;
    o.x = f2bf(v.x); o.y = f2bf(v.y); o.z = f2bf(v.z); o.w = f2bf(v.w);
    *(ushort4*)(Kb + (long)bh * (KV_ * D_) + rem) = o;
}

// cache_v f32 [bh][s][d] (s<2048) + Vn bf16 [bh][t][d] -> Vt bf16 [bh][d][s 0..4095]
__global__ void transpose_v(const float* __restrict__ cv, const u16* __restrict__ Vn,
                            u16* __restrict__ Vt) {
    __shared__ __align__(16) u16 tile[64][132];
    const int tid = threadIdx.x;
    const int bh = blockIdx.x >> 6;
    const int s0 = (blockIdx.x & 63) * 64;
    if (s0 < CL_) {
#pragma unroll
        for (int j = 0; j < 8; ++j) {
            int c = tid + j * 256;            // 2048 chunks of 4
            int sl = c >> 5, d0 = (c & 31) * 4;
            const float4 v = *(const float4*)(cv + ((long)bh * CL_ + s0 + sl) * D_ + d0);
            ushort4 o;
            o.x = f2bf(v.x); o.y = f2bf(v.y); o.z = f2bf(v.z); o.w = f2bf(v.w);
            *(ushort4*)&tile[sl][d0] = o;
        }
    } else {
#pragma unroll
        for (int j = 0; j < 8; ++j) {
            int c = tid + j * 256;
            int sl = c >> 5, d0 = (c & 31) * 4;
            ushort4 o = *(const ushort4*)(Vn + ((long)bh * T_ + s0 - CL_ + sl) * D_ + d0);
            *(ushort4*)&tile[sl][d0] = o;
        }
    }
    __syncthreads();
#pragma unroll
    for (int j = 0; j < 8; ++j) {
        int c = tid + j * 256;
        int d = c >> 4, sl0 = (c & 15) * 4;
        ushort4 o;
        o.x = tile[sl0 + 0][d]; o.y = tile[sl0 + 1][d];
        o.z = tile[sl0 + 2][d]; o.w = tile[sl0 + 3][d];
        *(ushort4*)(Vt + ((long)bh * D_ + d) * KV_ + s0 + sl0) = o;
    }
}

// ---------------- GEMM: C = A(MxK) * Bt(NxK)^T, bf16 in, fused epilogues ----------------

template <int MODE>
__global__ void gemm_bt(const u16* __restrict__ A, const u16* __restrict__ Bt,
                        int K,
                        u16* __restrict__ Qb, u16* __restrict__ Kb,
                        u16* __restrict__ Vn, float* __restrict__ Out) {
    __shared__ __align__(16) char A_lds[128 * 128];
    __shared__ __align__(16) char B_lds[128 * 128];

    const int tid = threadIdx.x;
    const int w = tid >> 6, l = tid & 63;
    const int wm = w >> 1, wn = w & 1;
    const int lg = l >> 4, lc = l & 15;
    const long m0 = (long)blockIdx.y * 128, n0 = (long)blockIdx.x * 128;

    f32x4 acc[4][4] = {};

    const char* Ab = (const char*)A + m0 * (K * 2);
    const char* Bb = (const char*)Bt + n0 * (K * 2);

    for (int k0 = 0; k0 < K; k0 += 64) {
#pragma unroll
        for (int j = 0; j < 4; ++j) {
            int o = ((w * 4 + j) << 10) + l * 16;
            int row = o >> 7, col = o & 127;
            gload16(Ab + (long)row * (K * 2) + k0 * 2 + col, A_lds + ((w * 4 + j) << 10));
            gload16(Bb + (long)row * (K * 2) + k0 * 2 + col, B_lds + ((w * 4 + j) << 10));
        }
        __syncthreads();
#pragma unroll
        for (int kk = 0; kk < 64; kk += 32) {
            short8 a[4], b[4];
#pragma unroll
            for (int f = 0; f < 4; ++f) {
                a[f] = *(const short8*)(A_lds + (wm * 64 + f * 16 + lc) * 128 + (kk + lg * 8) * 2);
                b[f] = *(const short8*)(B_lds + (wn * 64 + f * 16 + lc) * 128 + (kk + lg * 8) * 2);
            }
#pragma unroll
            for (int mf = 0; mf < 4; ++mf)
#pragma unroll
                for (int nf = 0; nf < 4; ++nf)
                    acc[mf][nf] = __builtin_amdgcn_mfma_f32_16x16x32_bf16(a[mf], b[nf], acc[mf][nf], 0, 0, 0);
        }
        __syncthreads();
    }

    const float qscale = 0.088388347648318447f;  // 128^-0.5
#pragma unroll
    for (int mf = 0; mf < 4; ++mf) {
#pragma unroll
        for (int nf = 0; nf < 4; ++nf) {
            int mbase = (int)m0 + wm * 64 + mf * 16 + lg * 4;
            int n = (int)n0 + wn * 64 + nf * 16 + lc;
#pragma unroll
            for (int r = 0; r < 4; ++r) {
                float c = acc[mf][nf][r];
                int m = mbase + r;
                if (MODE == 0) {
                    int b = m >> 11, t = m & 2047;
                    int sec = n >> 11, f = n & 2047;
                    int h = f >> 7, d = f & 127;
                    long bh = b * H_ + h;
                    if (sec == 0)      Qb[(bh * T_ + t) * D_ + d] = f2bf(c * qscale);
                    else if (sec == 1) Kb[(bh * KV_ + CL_ + t) * D_ + d] = f2bf(c);
                    else               Vn[(bh * T_ + t) * D_ + d] = f2bf(c);
                } else {
                    Out[(long)m * DM_ + n] = c;
                }
            }
        }
    }
}

// ---------------- flash attention ----------------
// grid: 1024 blocks, 256 threads = 4 waves, wave = 16 q rows, KV tile = 64
// K: LDS double-buffered (XOR-swizzled via pre-swizzled gload_lds source)
// V: direct global->register fragments (Vt layout is MFMA-B contiguous)
// block remap: bh pinned to XCD (L2 affinity), long q-tiles launch first

__global__ __launch_bounds__(256, 3) void attn_fwd(const u16* __restrict__ Qb,
                                                   const u16* __restrict__ Kb,
                                                   const u16* __restrict__ Vt,
                                                   u16* __restrict__ Yb) {
    __shared__ __align__(16) char K_lds[2][16384];
    __shared__ __align__(16) u16 P_lds[4 * 16 * 72];

    const int tid = threadIdx.x;
    const int w = tid >> 6, l = tid & 63;
    const int lg = l >> 4, lc = l & 15;
    const int blk = blockIdx.x;
    const int bh = (blk & 7) * 4 + (blk >> 8);        // 4 bh per XCD, phased
    const int q0 = (31 - ((blk >> 3) & 31)) * 64;     // long blocks first
    const int trow0 = q0 + w * 16;

    short8 qf[4];
    const u16* qp = Qb + ((long)bh * T_ + trow0 + lc) * D_;
#pragma unroll
    for (int ks = 0; ks < 4; ++ks) qf[ks] = *(const short8*)(qp + ks * 32 + lg * 8);

    f32x4 oacc[8] = {};
    float mrun[4] = {-1e38f, -1e38f, -1e38f, -1e38f};
    float lrun[4] = {0.f, 0.f, 0.f, 0.f};

    const char* kb = (const char*)Kb + (long)bh * KV_ * 256;
    const u16* vb = Vt + (long)bh * D_ * KV_;
    u16* pw = P_lds + w * (16 * 72);

    const int sEnd = q0 + CL_;  // last (triangular) tile start

    // prologue: stage K tile 0 into buffer 0
#pragma unroll
    for (int j = 0; j < 4; ++j) {
        int o = ((w * 4 + j) << 10) + l * 16;
        int s = o >> 8;
        gload16(kb + (o ^ ((s & 7) << 4)), K_lds[0] + ((w * 4 + j) << 10));
    }
    __syncthreads();

    int cur = 0;
    for (int s0 = 0; s0 <= sEnd; s0 += 64) {
        // V fragments for THIS tile -> registers (issued first so later waits
        // on them don't drain the K prefetch)
        short8 vf[16];
#pragma unroll
        for (int ks = 0; ks < 2; ++ks)
#pragma unroll
            for (int n = 0; n < 8; ++n)
                vf[ks * 8 + n] = *(const short8*)(vb + (long)(n * 16 + lc) * KV_ + s0 + ks * 32 + lg * 8);

        // prefetch NEXT K tile into the other buffer
        if (s0 + 64 <= sEnd) {
#pragma unroll
            for (int j = 0; j < 4; ++j) {
                int o = ((w * 4 + j) << 10) + l * 16;
                int s = o >> 8;
                gload16(kb + (long)(s0 + 64) * 256 + (o ^ ((s & 7) << 4)),
                        K_lds[cur ^ 1] + ((w * 4 + j) << 10));
            }
        }

        // S = Q K^T  (16 q rows x 64 s cols per wave)
        f32x4 sa[4] = {};
#pragma unroll
        for (int nf = 0; nf < 4; ++nf) {
            int srow = nf * 16 + lc;
            int sb = srow * 256, sw = (srow & 7) << 4;
#pragma unroll
            for (int ks = 0; ks < 4; ++ks) {
                short8 kf = *(const short8*)(K_lds[cur] + ((sb + (ks * 32 + lg * 8) * 2) ^ sw));
                sa[nf] = __builtin_amdgcn_mfma_f32_16x16x32_bf16(qf[ks], kf, sa[nf], 0, 0, 0);
            }
        }

        if (s0 + 64 > sEnd) {  // triangular tile
#pragma unroll
            for (int nf = 0; nf < 4; ++nf) {
                int scol = s0 + nf * 16 + lc;
#pragma unroll
                for (int r = 0; r < 4; ++r)
                    if (scol > trow0 + lg * 4 + r + CL_) sa[nf][r] = -3e38f;
            }
        }

        // online softmax (row stats across the 16 lanes of each group)
        float scl[4];
#pragma unroll
        for (int r = 0; r < 4; ++r) {
            float tm = fmaxf(fmaxf(sa[0][r], sa[1][r]), fmaxf(sa[2][r], sa[3][r]));
            tm = fmaxf(tm, __shfl_xor(tm, 1));
            tm = fmaxf(tm, __shfl_xor(tm, 2));
            tm = fmaxf(tm, __shfl_xor(tm, 4));
            tm = fmaxf(tm, __shfl_xor(tm, 8));
            float mnew = fmaxf(mrun[r], tm);
            scl[r] = __expf(mrun[r] - mnew);
            mrun[r] = mnew;
        }
#pragma unroll
        for (int nf = 0; nf < 4; ++nf)
#pragma unroll
            for (int r = 0; r < 4; ++r) sa[nf][r] = __expf(sa[nf][r] - mrun[r]);
#pragma unroll
        for (int r = 0; r < 4; ++r) {
            float ts = sa[0][r] + sa[1][r] + sa[2][r] + sa[3][r];
            ts += __shfl_xor(ts, 1);
            ts += __shfl_xor(ts, 2);
            ts += __shfl_xor(ts, 4);
            ts += __shfl_xor(ts, 8);
            lrun[r] = lrun[r] * scl[r] + ts;
        }
#pragma unroll
        for (int n = 0; n < 8; ++n)
#pragma unroll
            for (int r = 0; r < 4; ++r) oacc[n][r] *= scl[r];

        // P (C-layout) -> LDS -> A-layout fragments (per-wave region, no barrier)
#pragma unroll
        for (int nf = 0; nf < 4; ++nf)
#pragma unroll
            for (int r = 0; r < 4; ++r)
                pw[(lg * 4 + r) * 72 + nf * 16 + lc] = f2bf(sa[nf][r]);

#pragma unroll
        for (int ks = 0; ks < 2; ++ks) {
            short8 pf = *(const short8*)(pw + lc * 72 + ks * 32 + lg * 8);
#pragma unroll
            for (int n = 0; n < 8; ++n)
                oacc[n] = __builtin_amdgcn_mfma_f32_16x16x32_bf16(pf, vf[ks * 8 + n], oacc[n], 0, 0, 0);
        }

        __syncthreads();   // drains K(t+1) gloads; protects K_lds[cur] reuse
        cur ^= 1;
    }

    const int b = bh >> 4, h = bh & 15;
    float inv[4];
#pragma unroll
    for (int r = 0; r < 4; ++r) inv[r] = 1.0f / lrun[r];
#pragma unroll
    for (int n = 0; n < 8; ++n)
#pragma unroll
        for (int r = 0; r < 4; ++r) {
            int t = trow0 + lg * 4 + r;
            int c = h * D_ + n * 16 + lc;
            Yb[((long)b * T_ + t) * DM_ + c] = f2bf(oacc[n][r] * inv[r]);
        }
}

// ---------------- launch ----------------

extern "C" void kernel_launch(void* const* d_in, const int* in_sizes, int n_in,
                              void* d_out, int out_size, void* d_ws, size_t ws_size,
                              hipStream_t stream) {
    const float* x    = (const float*)d_in[0];
    const float* Wqkv = (const float*)d_in[1];
    const float* Wpr  = (const float*)d_in[2];
    const float* cK   = (const float*)d_in[3];
    const float* cV   = (const float*)d_in[4];
    float* out = (float*)d_out;

    char* p = (char*)d_ws;
    auto take = [&](long elems) { u16* r = (u16*)p; p += ((elems * 2 + 255) & ~255L); return r; };
    u16* xb  = take((long)B_ * T_ * DM_);        // x bf16 [4096][2048]
    u16* wqb = take((long)3 * DM_ * DM_);        // Wqkv bf16 [6144][2048]
    u16* wpb = take((long)DM_ * DM_);            // Wproj bf16 [2048][2048]
    u16* Qb  = take((long)B_ * H_ * T_ * D_);    // [bh][t][d], pre-scaled
    u16* Kb  = take((long)B_ * H_ * KV_ * D_);   // [bh][s(4096)][d]
    u16* Vt  = take((long)B_ * H_ * KV_ * D_);   // [bh][d][s(4096)]
    u16* Vn  = take((long)B_ * H_ * T_ * D_);    // new V [bh][t][d]
    u16* Yb  = take((long)B_ * T_ * DM_);        // attn out bf16 [4096][2048]

    cvt4<<<(B_ * T_ * DM_ / 4 + 255) / 256, 256, 0, stream>>>(x, xb, B_ * T_ * DM_ / 4);
    cvt4<<<(3 * DM_ * DM_ / 4 + 255) / 256, 256, 0, stream>>>(Wqkv, wqb, 3 * DM_ * DM_ / 4);
    cvt4<<<(DM_ * DM_ / 4 + 255) / 256, 256, 0, stream>>>(Wpr, wpb, DM_ * DM_ / 4);
    cvt_cachek<<<(B_ * H_ * CL_ * D_ / 4) / 256, 256, 0, stream>>>(cK, Kb);

    gemm_bt<0><<<dim3(48, 32), 256, 0, stream>>>(xb, wqb, 2048, Qb, Kb, Vn, nullptr);
    transpose_v<<<B_ * H_ * (KV_ / 64), 256, 0, stream>>>(cV, Vn, Vt);
    attn_fwd<<<B_ * H_ * (T_ / 64), 256, 0, stream>>>(Qb, Kb, Vt, Yb);
    gemm_bt<1><<<dim3(16, 32), 256, 0, stream>>>(Yb, wpb, 2048, nullptr, nullptr, nullptr, out);
}

// Round 7
// 540.279 us; speedup vs baseline: 1.7866x; 1.7866x over previous
//
#include <hip/hip_runtime.h>

#define B_ 2
#define T_ 2048
#define H_ 16
#define D_ 128
#define DM_ 2048
#define CL_ 2048
#define KV_ 4096

typedef __attribute__((ext_vector_type(8))) short short8;
typedef __attribute__((ext_vector_type(4))) float f32x4;
typedef __attribute__((ext_vector_type(16))) float f32x16;
typedef unsigned short u16;

__device__ __forceinline__ u16 f2bf(float f) {
    unsigned u = __float_as_uint(f);
    u += 0x7FFFu + ((u >> 16) & 1u);   // RNE to bf16
    return (u16)(u >> 16);
}

__device__ __forceinline__ void gload16(const void* g, void* l) {
    __builtin_amdgcn_global_load_lds((__attribute__((address_space(1))) const void*)g,
                                     (__attribute__((address_space(3))) void*)l, 16, 0, 0);
}

// ---------------- conversions ----------------

__global__ void cvt4(const float* __restrict__ src, u16* __restrict__ dst, int n4) {
    int i = blockIdx.x * 256 + threadIdx.x;
    if (i >= n4) return;
    const float4 v = *(const float4*)(src + (long)i * 4);
    ushort4 o;
    o.x = f2bf(v.x); o.y = f2bf(v.y); o.z = f2bf(v.z); o.w = f2bf(v.w);
    *(ushort4*)(dst + (long)i * 4) = o;
}

// cache_k f32 [bh][s<2048][d] -> Kc bf16 chunked [bh][kc16][s4096][8d]
__global__ void cvt_cachek(const float* __restrict__ ck, u16* __restrict__ Kc) {
    int i = blockIdx.x * 256 + threadIdx.x;     // 32*16*2048 threads
    int kc = i & 15, s = (i >> 4) & 2047, bh = i >> 15;
    const float* src = ck + ((long)bh * 2048 + s) * 128 + kc * 8;
    float4 v0 = *(const float4*)src, v1 = *(const float4*)(src + 4);
    short8 o;
    o[0] = f2bf(v0.x); o[1] = f2bf(v0.y); o[2] = f2bf(v0.z); o[3] = f2bf(v0.w);
    o[4] = f2bf(v1.x); o[5] = f2bf(v1.y); o[6] = f2bf(v1.z); o[7] = f2bf(v1.w);
    *(short8*)(Kc + ((long)(bh * 16 + kc) * 4096 + s) * 8) = o;
}

// cache_v f32 [bh][s<2048][d] -> Vc bf16 chunked [bh][sch512][d128][8s]
__global__ void cvt_cachev(const float* __restrict__ cv, u16* __restrict__ Vc) {
    int i = blockIdx.x * 256 + threadIdx.x;     // 32*256*128 threads (cache part)
    int d = i & 127, ch = (i >> 7) & 255, bh = i >> 15;
    const float* src = cv + ((long)bh * 2048 + ch * 8) * 128 + d;
    short8 o;
#pragma unroll
    for (int j = 0; j < 8; ++j) o[j] = f2bf(src[j * 128]);
    *(short8*)(Vc + ((long)(bh * 512 + ch) * 128 + d) * 8) = o;
}

// ---------------- GEMM: C = A(MxK) * Bt(NxK)^T, bf16 in, fused epilogues ----------------

template <int MODE>
__global__ void gemm_bt(const u16* __restrict__ A, const u16* __restrict__ Bt,
                        int K,
                        u16* __restrict__ Qb, u16* __restrict__ Kc,
                        u16* __restrict__ Vc, float* __restrict__ Out) {
    __shared__ __align__(16) char A_lds[128 * 128];
    __shared__ __align__(16) char B_lds[128 * 128];

    const int tid = threadIdx.x;
    const int w = tid >> 6, l = tid & 63;
    const int wm = w >> 1, wn = w & 1;
    const int lg = l >> 4, lc = l & 15;
    const long m0 = (long)blockIdx.y * 128, n0 = (long)blockIdx.x * 128;

    f32x4 acc[4][4] = {};

    const char* Ab = (const char*)A + m0 * (K * 2);
    const char* Bb = (const char*)Bt + n0 * (K * 2);

    for (int k0 = 0; k0 < K; k0 += 64) {
#pragma unroll
        for (int j = 0; j < 4; ++j) {
            int o = ((w * 4 + j) << 10) + l * 16;
            int row = o >> 7, col = o & 127;
            gload16(Ab + (long)row * (K * 2) + k0 * 2 + col, A_lds + ((w * 4 + j) << 10));
            gload16(Bb + (long)row * (K * 2) + k0 * 2 + col, B_lds + ((w * 4 + j) << 10));
        }
        __syncthreads();
#pragma unroll
        for (int kk = 0; kk < 64; kk += 32) {
            short8 a[4], b[4];
#pragma unroll
            for (int f = 0; f < 4; ++f) {
                a[f] = *(const short8*)(A_lds + (wm * 64 + f * 16 + lc) * 128 + (kk + lg * 8) * 2);
                b[f] = *(const short8*)(B_lds + (wn * 64 + f * 16 + lc) * 128 + (kk + lg * 8) * 2);
            }
#pragma unroll
            for (int mf = 0; mf < 4; ++mf)
#pragma unroll
                for (int nf = 0; nf < 4; ++nf)
                    acc[mf][nf] = __builtin_amdgcn_mfma_f32_16x16x32_bf16(a[mf], b[nf], acc[mf][nf], 0, 0, 0);
        }
        __syncthreads();
    }

    const float qscale = 0.088388347648318447f;  // 128^-0.5
#pragma unroll
    for (int mf = 0; mf < 4; ++mf) {
#pragma unroll
        for (int nf = 0; nf < 4; ++nf) {
            int mbase = (int)m0 + wm * 64 + mf * 16 + lg * 4;
            int n = (int)n0 + wn * 64 + nf * 16 + lc;
#pragma unroll
            for (int r = 0; r < 4; ++r) {
                float c = acc[mf][nf][r];
                int m = mbase + r;
                if (MODE == 0) {
                    int b = m >> 11, t = m & 2047;
                    int sec = n >> 11, f = n & 2047;
                    int h = f >> 7, d = f & 127;
                    long bh = b * H_ + h;
                    int s = CL_ + t;
                    if (sec == 0)      Qb[(bh * T_ + t) * D_ + d] = f2bf(c * qscale);
                    else if (sec == 1) Kc[((bh * 16 + (d >> 3)) * 4096L + s) * 8 + (d & 7)] = f2bf(c);
                    else               Vc[((bh * 512 + (s >> 3)) * 128L + d) * 8 + (s & 7)] = f2bf(c);
                } else {
                    Out[(long)m * DM_ + n] = c;
                }
            }
        }
    }
}

// ---------------- flash attention (swapped-QK^T, 32x32, in-register softmax) ----------------
// 4 warps x 32 q-rows (block = 128 q), KVBLK = 64, K+V LDS double-buffered.
// Klds [kc16][s64][16B], Vlds [sch8][d128][16B] -> all ds_read_b128 conflict-free.
// S^T = mfma(K, Q): lane holds P[s=0..63][q=lane&31]; softmax in-register.
// All cross-lane traffic via verified __shfl/__shfl_xor (no permlane/cvt_pk).

__global__ __launch_bounds__(256, 2) void attn_fwd(const u16* __restrict__ Qb,
                                                   const u16* __restrict__ Kc,
                                                   const u16* __restrict__ Vc,
                                                   u16* __restrict__ Yb) {
    __shared__ __align__(16) char Klds[2][16384];
    __shared__ __align__(16) char Vlds[2][16384];

    const int tid = threadIdx.x;
    const int w = tid >> 6, l = tid & 63;
    const int col = l & 31, half = l >> 5;
    const int blk = blockIdx.x;
    const int xcd = blk & 7, ii = blk >> 3;
    const int bh = xcd * 4 + (ii >> 4);             // 4 bh pinned per XCD
    const int q0 = (15 - (ii & 15)) << 7;           // long blocks first
    const int qw0 = q0 + w * 32;

    const char* kcb = (const char*)Kc + (long)bh * 1048576;   // 16*4096*16
    const char* vcb = (const char*)Vc + (long)bh * 1048576;   // 512*128*16

    // Q B-fragments: lane holds Q[qw0+col][kmf*16 + half*8 .. +7]
    short8 qf[8];
    const u16* qp = Qb + ((long)bh * T_ + qw0 + col) * D_ + half * 8;
#pragma unroll
    for (int kmf = 0; kmf < 8; ++kmf) qf[kmf] = *(const short8*)(qp + kmf * 16);

    f32x16 oa[4] = {};
    float mrun = -1e38f, lrun = 0.f;

    auto stage = [&](int s0, int b) {
#pragma unroll
        for (int j = 0; j < 4; ++j) {
            int kc = w * 4 + j;
            gload16(kcb + (long)kc * 65536 + (long)(s0 + l) * 16, Klds[b] + kc * 1024);
            gload16(vcb + (long)s0 * 256 + (long)(kc * 64 + l) * 16, Vlds[b] + kc * 1024);
        }
    };

    stage(0, 0);
    __syncthreads();

    const int sLast = q0 + 2112;   // q0 + BQ - 64 + CL_
    int cur = 0;
    for (int s0 = 0; s0 <= sLast; s0 += 64) {
        if (s0 < sLast) stage(s0 + 64, cur ^ 1);

        if (s0 <= qw0 + 31 + CL_) {    // warp-uniform: any unmasked key in tile
            // ---- S^T = K * Q^T : p0 = s[0..31], p1 = s[32..63], q = col ----
            f32x16 p0 = {}, p1 = {};
#pragma unroll
            for (int kmf = 0; kmf < 8; ++kmf) {
                const char* kbase = Klds[cur] + (((kmf * 2 + half) * 64 + col) << 4);
                short8 kf0 = *(const short8*)(kbase);
                short8 kf1 = *(const short8*)(kbase + (32 << 4));
                p0 = __builtin_amdgcn_mfma_f32_32x32x16_bf16(kf0, qf[kmf], p0, 0, 0, 0);
                p1 = __builtin_amdgcn_mfma_f32_32x32x16_bf16(kf1, qf[kmf], p1, 0, 0, 0);
            }

            // ---- causal mask (only near-diagonal tiles) ----
            if (s0 + 63 > qw0 + CL_) {
                int qg = qw0 + col + CL_;
#pragma unroll
                for (int r = 0; r < 16; ++r) {
                    int sl = s0 + (r & 3) + 8 * (r >> 2) + 4 * half;
                    if (sl > qg)      p0[r] = -3e38f;
                    if (sl + 32 > qg) p1[r] = -3e38f;
                }
            }

            // ---- row max (reg tree + cross-half shfl) ----
            float m8[8];
#pragma unroll
            for (int i = 0; i < 8; ++i)
                m8[i] = fmaxf(fmaxf(p0[i], p0[i + 8]), fmaxf(p1[i], p1[i + 8]));
            float pmax = fmaxf(fmaxf(fmaxf(m8[0], m8[1]), fmaxf(m8[2], m8[3])),
                               fmaxf(fmaxf(m8[4], m8[5]), fmaxf(m8[6], m8[7])));
            pmax = fmaxf(pmax, __shfl_xor(pmax, 32));

            // ---- online rescale (exact skip when max did not grow) ----
            if (!__all(pmax - mrun <= 0.0f)) {
                float mnew = fmaxf(mrun, pmax);
                float scl = __expf(mrun - mnew);
                mrun = mnew;
                lrun *= scl;
                float sc[16];
#pragma unroll
                for (int r = 0; r < 16; ++r) sc[r] = __shfl(scl, (r & 3) + 8 * (r >> 2) + 4 * half);
#pragma unroll
                for (int db = 0; db < 4; ++db)
#pragma unroll
                    for (int r = 0; r < 16; ++r) oa[db][r] *= sc[r];
            }

            // ---- exp + row sum ----
#pragma unroll
            for (int r = 0; r < 16; ++r) {
                p0[r] = __expf(p0[r] - mrun);
                p1[r] = __expf(p1[r] - mrun);
            }
            float s8[8];
#pragma unroll
            for (int i = 0; i < 8; ++i) s8[i] = (p0[i] + p0[i + 8]) + (p1[i] + p1[i + 8]);
            float ts = ((s8[0] + s8[1]) + (s8[2] + s8[3])) + ((s8[4] + s8[5]) + (s8[6] + s8[7]));
            lrun += ts + __shfl_xor(ts, 32);

            // ---- pack P to bf16 A-fragments (f2bf + cross-half shfl_xor) ----
            // consumer (c,h) needs s = smf*16 + h*8 + j; holder half = (s>>2)&1.
            short8 pa[4];
#pragma unroll
            for (int smf = 0; smf < 4; ++smf) {
                const f32x16& pp = (smf < 2) ? p0 : p1;
                const int r0 = (smf & 1) * 8;
                unsigned Alo = (unsigned)f2bf(pp[r0 + 0]) | ((unsigned)f2bf(pp[r0 + 1]) << 16);
                unsigned Ahi = (unsigned)f2bf(pp[r0 + 2]) | ((unsigned)f2bf(pp[r0 + 3]) << 16);
                unsigned Blo = (unsigned)f2bf(pp[r0 + 4]) | ((unsigned)f2bf(pp[r0 + 5]) << 16);
                unsigned Bhi = (unsigned)f2bf(pp[r0 + 6]) | ((unsigned)f2bf(pp[r0 + 7]) << 16);
                unsigned sAlo = __shfl_xor(Alo, 32), sAhi = __shfl_xor(Ahi, 32);
                unsigned sBlo = __shfl_xor(Blo, 32), sBhi = __shfl_xor(Bhi, 32);
                union { unsigned u[4]; short8 s; } U;
                if (half == 0) { U.u[0] = Alo;  U.u[1] = Ahi;  U.u[2] = sAlo; U.u[3] = sAhi; }
                else           { U.u[0] = sBlo; U.u[1] = sBhi; U.u[2] = Blo;  U.u[3] = Bhi; }
                pa[smf] = U.s;
            }

            // ---- O += P * V ----
#pragma unroll
            for (int db = 0; db < 4; ++db) {
#pragma unroll
                for (int smf = 0; smf < 4; ++smf) {
                    short8 vf = *(const short8*)(Vlds[cur] + (((smf * 2 + half) * 128 + db * 32 + col) << 4));
                    oa[db] = __builtin_amdgcn_mfma_f32_32x32x16_bf16(pa[smf], vf, oa[db], 0, 0, 0);
                }
            }
        }

        __syncthreads();
        cur ^= 1;
    }

    // ---- epilogue: normalize and store ----
    float inv = 1.0f / lrun;
    float li[16];
#pragma unroll
    for (int r = 0; r < 16; ++r) li[r] = __shfl(inv, (r & 3) + 8 * (r >> 2) + 4 * half);

    const int b = bh >> 4, h = bh & 15;
#pragma unroll
    for (int db = 0; db < 4; ++db)
#pragma unroll
        for (int r = 0; r < 16; ++r) {
            int t = qw0 + (r & 3) + 8 * (r >> 2) + 4 * half;
            Yb[((long)b * T_ + t) * DM_ + h * 128 + db * 32 + col] = f2bf(oa[db][r] * li[r]);
        }
}

// ---------------- launch ----------------

extern "C" void kernel_launch(void* const* d_in, const int* in_sizes, int n_in,
                              void* d_out, int out_size, void* d_ws, size_t ws_size,
                              hipStream_t stream) {
    const float* x    = (const float*)d_in[0];
    const float* Wqkv = (const float*)d_in[1];
    const float* Wpr  = (const float*)d_in[2];
    const float* cK   = (const float*)d_in[3];
    const float* cV   = (const float*)d_in[4];
    float* out = (float*)d_out;

    char* p = (char*)d_ws;
    auto take = [&](long elems) { u16* r = (u16*)p; p += ((elems * 2 + 255) & ~255L); return r; };
    u16* xb  = take((long)B_ * T_ * DM_);        // x bf16
    u16* wqb = take((long)3 * DM_ * DM_);        // Wqkv bf16
    u16* wpb = take((long)DM_ * DM_);            // Wproj bf16
    u16* Qb  = take((long)B_ * H_ * T_ * D_);    // [bh][t][d], pre-scaled
    u16* Kc  = take((long)B_ * H_ * KV_ * D_);   // chunked [bh][kc16][s][8d]
    u16* Vc  = take((long)B_ * H_ * KV_ * D_);   // chunked [bh][sch][d][8s]
    u16* Yb  = take((long)B_ * T_ * DM_);        // attn out bf16

    cvt4<<<(B_ * T_ * DM_ / 4 + 255) / 256, 256, 0, stream>>>(x, xb, B_ * T_ * DM_ / 4);
    cvt4<<<(3 * DM_ * DM_ / 4 + 255) / 256, 256, 0, stream>>>(Wqkv, wqb, 3 * DM_ * DM_ / 4);
    cvt4<<<(DM_ * DM_ / 4 + 255) / 256, 256, 0, stream>>>(Wpr, wpb, DM_ * DM_ / 4);
    cvt_cachek<<<(32 * 16 * 2048) / 256, 256, 0, stream>>>(cK, Kc);
    cvt_cachev<<<(32 * 256 * 128) / 256, 256, 0, stream>>>(cV, Vc);

    gemm_bt<0><<<dim3(48, 32), 256, 0, stream>>>(xb, wqb, 2048, Qb, Kc, Vc, nullptr);
    attn_fwd<<<512, 256, 0, stream>>>(Qb, Kc, Vc, Yb);
    gemm_bt<1><<<dim3(16, 32), 256, 0, stream>>>(Yb, wpb, 2048, nullptr, nullptr, nullptr, out);
}

// Round 8
// 522.219 us; speedup vs baseline: 1.8484x; 1.0346x over previous
//
#include <hip/hip_runtime.h>

#define B_ 2
#define T_ 2048
#define H_ 16
#define D_ 128
#define DM_ 2048
#define CL_ 2048
#define KV_ 4096

typedef __attribute__((ext_vector_type(8))) short short8;
typedef __attribute__((ext_vector_type(4))) float f32x4;
typedef __attribute__((ext_vector_type(16))) float f32x16;
typedef unsigned short u16;

__device__ __forceinline__ u16 f2bf(float f) {
    unsigned u = __float_as_uint(f);
    u += 0x7FFFu + ((u >> 16) & 1u);   // RNE to bf16
    return (u16)(u >> 16);
}

__device__ __forceinline__ void gload16(const void* g, void* l) {
    __builtin_amdgcn_global_load_lds((__attribute__((address_space(1))) const void*)g,
                                     (__attribute__((address_space(3))) void*)l, 16, 0, 0);
}

// ---------------- conversions ----------------

__global__ void cvt4(const float* __restrict__ src, u16* __restrict__ dst, int n4) {
    int i = blockIdx.x * 256 + threadIdx.x;
    if (i >= n4) return;
    const float4 v = *(const float4*)(src + (long)i * 4);
    ushort4 o;
    o.x = f2bf(v.x); o.y = f2bf(v.y); o.z = f2bf(v.z); o.w = f2bf(v.w);
    *(ushort4*)(dst + (long)i * 4) = o;
}

// cache_k f32 [bh][s<2048][d] -> Kc bf16 chunked [bh][kc16][s4096][8d]
__global__ void cvt_cachek(const float* __restrict__ ck, u16* __restrict__ Kc) {
    int i = blockIdx.x * 256 + threadIdx.x;     // 32*16*2048 threads
    int kc = i & 15, s = (i >> 4) & 2047, bh = i >> 15;
    const float* src = ck + ((long)bh * 2048 + s) * 128 + kc * 8;
    float4 v0 = *(const float4*)src, v1 = *(const float4*)(src + 4);
    short8 o;
    o[0] = f2bf(v0.x); o[1] = f2bf(v0.y); o[2] = f2bf(v0.z); o[3] = f2bf(v0.w);
    o[4] = f2bf(v1.x); o[5] = f2bf(v1.y); o[6] = f2bf(v1.z); o[7] = f2bf(v1.w);
    *(short8*)(Kc + ((long)(bh * 16 + kc) * 4096 + s) * 8) = o;
}

// cache_v f32 [bh][s<2048][d] -> Vc bf16 chunked [bh][sch512][d128][8s]
__global__ void cvt_cachev(const float* __restrict__ cv, u16* __restrict__ Vc) {
    int i = blockIdx.x * 256 + threadIdx.x;     // 32*256*128 threads (cache part)
    int d = i & 127, ch = (i >> 7) & 255, bh = i >> 15;
    const float* src = cv + ((long)bh * 2048 + ch * 8) * 128 + d;
    short8 o;
#pragma unroll
    for (int j = 0; j < 8; ++j) o[j] = f2bf(src[j * 128]);
    *(short8*)(Vc + ((long)(bh * 512 + ch) * 128 + d) * 8) = o;
}

// ---------------- GEMM: C = A(MxK) * Bt(NxK)^T, bf16 in, fused epilogues ----------------

template <int MODE>
__global__ void gemm_bt(const u16* __restrict__ A, const u16* __restrict__ Bt,
                        int K,
                        u16* __restrict__ Qb, u16* __restrict__ Kc,
                        u16* __restrict__ Vc, float* __restrict__ Out) {
    __shared__ __align__(16) char A_lds[128 * 128];
    __shared__ __align__(16) char B_lds[128 * 128];

    const int tid = threadIdx.x;
    const int w = tid >> 6, l = tid & 63;
    const int wm = w >> 1, wn = w & 1;
    const int lg = l >> 4, lc = l & 15;
    const long m0 = (long)blockIdx.y * 128, n0 = (long)blockIdx.x * 128;

    f32x4 acc[4][4] = {};

    const char* Ab = (const char*)A + m0 * (K * 2);
    const char* Bb = (const char*)Bt + n0 * (K * 2);

    for (int k0 = 0; k0 < K; k0 += 64) {
#pragma unroll
        for (int j = 0; j < 4; ++j) {
            int o = ((w * 4 + j) << 10) + l * 16;
            int row = o >> 7, col = o & 127;
            gload16(Ab + (long)row * (K * 2) + k0 * 2 + col, A_lds + ((w * 4 + j) << 10));
            gload16(Bb + (long)row * (K * 2) + k0 * 2 + col, B_lds + ((w * 4 + j) << 10));
        }
        __syncthreads();
#pragma unroll
        for (int kk = 0; kk < 64; kk += 32) {
            short8 a[4], b[4];
#pragma unroll
            for (int f = 0; f < 4; ++f) {
                a[f] = *(const short8*)(A_lds + (wm * 64 + f * 16 + lc) * 128 + (kk + lg * 8) * 2);
                b[f] = *(const short8*)(B_lds + (wn * 64 + f * 16 + lc) * 128 + (kk + lg * 8) * 2);
            }
#pragma unroll
            for (int mf = 0; mf < 4; ++mf)
#pragma unroll
                for (int nf = 0; nf < 4; ++nf)
                    acc[mf][nf] = __builtin_amdgcn_mfma_f32_16x16x32_bf16(a[mf], b[nf], acc[mf][nf], 0, 0, 0);
        }
        __syncthreads();
    }

    const float qscale = 0.088388347648318447f;  // 128^-0.5
#pragma unroll
    for (int mf = 0; mf < 4; ++mf) {
#pragma unroll
        for (int nf = 0; nf < 4; ++nf) {
            int mbase = (int)m0 + wm * 64 + mf * 16 + lg * 4;
            int n = (int)n0 + wn * 64 + nf * 16 + lc;
#pragma unroll
            for (int r = 0; r < 4; ++r) {
                float c = acc[mf][nf][r];
                int m = mbase + r;
                if (MODE == 0) {
                    int b = m >> 11, t = m & 2047;
                    int sec = n >> 11, f = n & 2047;
                    int h = f >> 7, d = f & 127;
                    long bh = b * H_ + h;
                    int s = CL_ + t;
                    if (sec == 0)      Qb[(bh * T_ + t) * D_ + d] = f2bf(c * qscale);
                    else if (sec == 1) Kc[((bh * 16 + (d >> 3)) * 4096L + s) * 8 + (d & 7)] = f2bf(c);
                    else               Vc[((bh * 512 + (s >> 3)) * 128L + d) * 8 + (s & 7)] = f2bf(c);
                } else {
                    Out[(long)m * DM_ + n] = c;
                }
            }
        }
    }
}

// ---------------- flash attention (swapped-QK^T, 32x32, in-register softmax) ----------------
// 4 warps x 32 q-rows (block = 128 q), KVBLK = 64.
// K: LDS double-buffered, chunked [kc16][s64][16B] -> conflict-free ds_read_b128.
// V: straight from global (L2) into register fragments, issued at tile top so
//    QK^T+softmax hides the latency; PV waits vmcnt(8) leaving K prefetch in flight.
// Block remap: co-resident blocks (blk, blk+256) get complementary-length q-tiles.

__global__ __launch_bounds__(256, 2) void attn_fwd(const u16* __restrict__ Qb,
                                                   const u16* __restrict__ Kc,
                                                   const u16* __restrict__ Vc,
                                                   u16* __restrict__ Yb) {
    __shared__ __align__(16) char Klds[2][16384];

    const int tid = threadIdx.x;
    const int w = tid >> 6, l = tid & 63;
    const int col = l & 31, half = l >> 5;
    const int blk = blockIdx.x;
    const int xcd = blk & 7, ii = blk >> 3;
    const int bh = xcd * 4 + ((ii >> 4) & 1) + (((ii >> 5) & 1) << 1);  // 4 bh per XCD
    const int q0 = ((ii & 32) ? (15 - (ii & 15)) : (ii & 15)) << 7;     // complementary pairs
    const int qw0 = q0 + w * 32;

    const char* kcb = (const char*)Kc + (long)bh * 1048576;   // 16*4096*16
    const char* vcb = (const char*)Vc + (long)bh * 1048576;   // 512*128*16

    // Q B-fragments: lane holds Q[qw0+col][kmf*16 + half*8 .. +7]
    short8 qf[8];
    const u16* qp = Qb + ((long)bh * T_ + qw0 + col) * D_ + half * 8;
#pragma unroll
    for (int kmf = 0; kmf < 8; ++kmf) qf[kmf] = *(const short8*)(qp + kmf * 16);

    f32x16 oa[4] = {};
    float mrun = -1e38f, lrun = 0.f;

    auto stageK = [&](int s0, int b) {
#pragma unroll
        for (int j = 0; j < 4; ++j) {
            int kc = w * 4 + j;
            gload16(kcb + (long)kc * 65536 + (long)(s0 + l) * 16, Klds[b] + kc * 1024);
        }
    };

    stageK(0, 0);
    __syncthreads();

    const int sLast = q0 + 2112;   // q0 + BQ - 64 + CL_
    int cur = 0;
    for (int s0 = 0; s0 <= sLast; s0 += 64) {
        const bool active = (s0 <= qw0 + 31 + CL_);   // warp-uniform

        // ---- V fragments for THIS tile -> registers (issued before K prefetch
        //      so PV's first-use wait is vmcnt(8), not vmcnt(0)) ----
        short8 vf[16];
        if (active) {
            const char* vsrc = vcb + (long)s0 * 256;
#pragma unroll
            for (int db = 0; db < 4; ++db)
#pragma unroll
                for (int smf = 0; smf < 4; ++smf)
                    vf[db * 4 + smf] =
                        *(const short8*)(vsrc + (((smf * 2 + half) * 128 + db * 32 + col) << 4));
        }

        if (s0 < sLast) stageK(s0 + 64, cur ^ 1);

        if (active) {
            // ---- S^T = K * Q^T : p0 = s[0..31], p1 = s[32..63], q = col ----
            f32x16 p0 = {}, p1 = {};
#pragma unroll
            for (int kmf = 0; kmf < 8; ++kmf) {
                const char* kbase = Klds[cur] + (((kmf * 2 + half) * 64 + col) << 4);
                short8 kf0 = *(const short8*)(kbase);
                short8 kf1 = *(const short8*)(kbase + (32 << 4));
                p0 = __builtin_amdgcn_mfma_f32_32x32x16_bf16(kf0, qf[kmf], p0, 0, 0, 0);
                p1 = __builtin_amdgcn_mfma_f32_32x32x16_bf16(kf1, qf[kmf], p1, 0, 0, 0);
            }

            // ---- causal mask (only near-diagonal tiles) ----
            if (s0 + 63 > qw0 + CL_) {
                int qg = qw0 + col + CL_;
#pragma unroll
                for (int r = 0; r < 16; ++r) {
                    int sl = s0 + (r & 3) + 8 * (r >> 2) + 4 * half;
                    if (sl > qg)      p0[r] = -3e38f;
                    if (sl + 32 > qg) p1[r] = -3e38f;
                }
            }

            // ---- row max (reg tree + cross-half shfl) ----
            float m8[8];
#pragma unroll
            for (int i = 0; i < 8; ++i)
                m8[i] = fmaxf(fmaxf(p0[i], p0[i + 8]), fmaxf(p1[i], p1[i + 8]));
            float pmax = fmaxf(fmaxf(fmaxf(m8[0], m8[1]), fmaxf(m8[2], m8[3])),
                               fmaxf(fmaxf(m8[4], m8[5]), fmaxf(m8[6], m8[7])));
            pmax = fmaxf(pmax, __shfl_xor(pmax, 32));

            // ---- online rescale (exact skip when max did not grow) ----
            if (!__all(pmax - mrun <= 0.0f)) {
                float mnew = fmaxf(mrun, pmax);
                float scl = __expf(mrun - mnew);
                mrun = mnew;
                lrun *= scl;
                float sc[16];
#pragma unroll
                for (int r = 0; r < 16; ++r) sc[r] = __shfl(scl, (r & 3) + 8 * (r >> 2) + 4 * half);
#pragma unroll
                for (int db = 0; db < 4; ++db)
#pragma unroll
                    for (int r = 0; r < 16; ++r) oa[db][r] *= sc[r];
            }

            // ---- exp + row sum ----
#pragma unroll
            for (int r = 0; r < 16; ++r) {
                p0[r] = __expf(p0[r] - mrun);
                p1[r] = __expf(p1[r] - mrun);
            }
            float s8[8];
#pragma unroll
            for (int i = 0; i < 8; ++i) s8[i] = (p0[i] + p0[i + 8]) + (p1[i] + p1[i + 8]);
            float ts = ((s8[0] + s8[1]) + (s8[2] + s8[3])) + ((s8[4] + s8[5]) + (s8[6] + s8[7]));
            lrun += ts + __shfl_xor(ts, 32);

            // ---- pack P to bf16 A-fragments (f2bf + cross-half shfl_xor) ----
            // consumer (c,h) needs s = smf*16 + h*8 + j; holder half = (s>>2)&1.
            short8 pa[4];
#pragma unroll
            for (int smf = 0; smf < 4; ++smf) {
                const f32x16& pp = (smf < 2) ? p0 : p1;
                const int r0 = (smf & 1) * 8;
                unsigned Alo = (unsigned)f2bf(pp[r0 + 0]) | ((unsigned)f2bf(pp[r0 + 1]) << 16);
                unsigned Ahi = (unsigned)f2bf(pp[r0 + 2]) | ((unsigned)f2bf(pp[r0 + 3]) << 16);
                unsigned Blo = (unsigned)f2bf(pp[r0 + 4]) | ((unsigned)f2bf(pp[r0 + 5]) << 16);
                unsigned Bhi = (unsigned)f2bf(pp[r0 + 6]) | ((unsigned)f2bf(pp[r0 + 7]) << 16);
                unsigned sAlo = __shfl_xor(Alo, 32), sAhi = __shfl_xor(Ahi, 32);
                unsigned sBlo = __shfl_xor(Blo, 32), sBhi = __shfl_xor(Bhi, 32);
                union { unsigned u[4]; short8 s; } U;
                if (half == 0) { U.u[0] = Alo;  U.u[1] = Ahi;  U.u[2] = sAlo; U.u[3] = sAhi; }
                else           { U.u[0] = sBlo; U.u[1] = sBhi; U.u[2] = Blo;  U.u[3] = Bhi; }
                pa[smf] = U.s;
            }

            // ---- O += P * V (vf from global; first use waits vmcnt(8)) ----
#pragma unroll
            for (int db = 0; db < 4; ++db) {
#pragma unroll
                for (int smf = 0; smf < 4; ++smf)
                    oa[db] = __builtin_amdgcn_mfma_f32_32x32x16_bf16(pa[smf], vf[db * 4 + smf], oa[db], 0, 0, 0);
            }
        }

        __syncthreads();
        cur ^= 1;
    }

    // ---- epilogue: normalize and store ----
    float inv = 1.0f / lrun;
    float li[16];
#pragma unroll
    for (int r = 0; r < 16; ++r) li[r] = __shfl(inv, (r & 3) + 8 * (r >> 2) + 4 * half);

    const int b = bh >> 4, h = bh & 15;
#pragma unroll
    for (int db = 0; db < 4; ++db)
#pragma unroll
        for (int r = 0; r < 16; ++r) {
            int t = qw0 + (r & 3) + 8 * (r >> 2) + 4 * half;
            Yb[((long)b * T_ + t) * DM_ + h * 128 + db * 32 + col] = f2bf(oa[db][r] * li[r]);
        }
}

// ---------------- launch ----------------

extern "C" void kernel_launch(void* const* d_in, const int* in_sizes, int n_in,
                              void* d_out, int out_size, void* d_ws, size_t ws_size,
                              hipStream_t stream) {
    const float* x    = (const float*)d_in[0];
    const float* Wqkv = (const float*)d_in[1];
    const float* Wpr  = (const float*)d_in[2];
    const float* cK   = (const float*)d_in[3];
    const float* cV   = (const float*)d_in[4];
    float* out = (float*)d_out;

    char* p = (char*)d_ws;
    auto take = [&](long elems) { u16* r = (u16*)p; p += ((elems * 2 + 255) & ~255L); return r; };
    u16* xb  = take((long)B_ * T_ * DM_);        // x bf16
    u16* wqb = take((long)3 * DM_ * DM_);        // Wqkv bf16
    u16* wpb = take((long)DM_ * DM_);            // Wproj bf16
    u16* Qb  = take((long)B_ * H_ * T_ * D_);    // [bh][t][d], pre-scaled
    u16* Kc  = take((long)B_ * H_ * KV_ * D_);   // chunked [bh][kc16][s][8d]
    u16* Vc  = take((long)B_ * H_ * KV_ * D_);   // chunked [bh][sch][d][8s]
    u16* Yb  = take((long)B_ * T_ * DM_);        // attn out bf16

    cvt4<<<(B_ * T_ * DM_ / 4 + 255) / 256, 256, 0, stream>>>(x, xb, B_ * T_ * DM_ / 4);
    cvt4<<<(3 * DM_ * DM_ / 4 + 255) / 256, 256, 0, stream>>>(Wqkv, wqb, 3 * DM_ * DM_ / 4);
    cvt4<<<(DM_ * DM_ / 4 + 255) / 256, 256, 0, stream>>>(Wpr, wpb, DM_ * DM_ / 4);
    cvt_cachek<<<(32 * 16 * 2048) / 256, 256, 0, stream>>>(cK, Kc);
    cvt_cachev<<<(32 * 256 * 128) / 256, 256, 0, stream>>>(cV, Vc);

    gemm_bt<0><<<dim3(48, 32), 256, 0, stream>>>(xb, wqb, 2048, Qb, Kc, Vc, nullptr);
    attn_fwd<<<512, 256, 0, stream>>>(Qb, Kc, Vc, Yb);
    gemm_bt<1><<<dim3(16, 32), 256, 0, stream>>>(Yb, wpb, 2048, nullptr, nullptr, nullptr, out);
}